// Round 6
// baseline (85.005 us; speedup 1.0000x reference)
//
#include <hip/hip_runtime.h>
#include <hip/hip_fp8.h>

#define N 8192
#define D 200
#define KP 232             // fp8 row stride BYTES: 58 dwords, gcd(58,32)=2 -> low LDS aliasing
#define NSTEP 7            // 7 * 32 = 224 K fed to MFMA (200 real + fp8-zero pad)
#define TB 128             // tile edge, ONE TILE PER BLOCK (8 waves, 64x32 quadrant each)
#define NT 64              // tile grid dim = N/TB
#define TPP 65             // tiles per row-pair: row q has 64-q, row 63-q has q+1
#define NBLK (32 * TPP)    // 2080 triangle tiles == blocks
#define PANEL (TB * KP)    // 29696 B, contiguous in global AND in LDS
#define NCELL 256

typedef float f32x4 __attribute__((ext_vector_type(4)));
#define AS3 __attribute__((address_space(3)))
#define AS1 __attribute__((address_space(1)))

// ---- prep: cast to fp8 e4m3 (padded to KP), row norms from fp8-decoded ----
// Block 0 also zeroes the 256 reduction cells (workspace is poisoned each iter).
__global__ __launch_bounds__(256) void prep_kernel(
    const float* __restrict__ x, const int* __restrict__ labels,
    unsigned char* __restrict__ xb, float* __restrict__ sq,
    int* __restrict__ lab, double* __restrict__ cells) {
  if (blockIdx.x == 0) cells[threadIdx.x] = 0.0;   // NCELL == blockDim
  int row = blockIdx.x * 4 + (threadIdx.x >> 6);   // one wave per row
  int lane = threadIdx.x & 63;
  const float* xr = x + (size_t)row * D;
  unsigned char* xbr = xb + (size_t)row * KP;
  int k0 = lane * 4;
  float4 f = {0.f, 0.f, 0.f, 0.f};
  if (k0 < D) f = *(const float4*)(xr + k0);       // lane<50 fully in-bounds
  float s = 0.f;
  unsigned char q[4];
  float ff[4] = {f.x, f.y, f.z, f.w};
#pragma unroll
  for (int c = 0; c < 4; ++c) {
    float v = (k0 + c < D) ? ff[c] : 0.f;
    __hip_fp8_e4m3 h(v);                           // OCP e4m3 RNE
    q[c] = h.__x;
    float fb = (float)h;
    s += fb * fb;                                  // norm of the fp8-rounded row
  }
  if (k0 < KP) *(uchar4*)(xbr + k0) = *(uchar4*)q; // lanes 0..57 (56,57 write zeros)
#pragma unroll
  for (int m = 32; m; m >>= 1) s += __shfl_xor(s, m);
  if (lane == 0) {
    sq[row] = s;
    lab[row] = labels[row];
  }
}

// ---- gram: one 128x128 tile per 512-THREAD block (8 waves, 64x32 each).
// ---- Same LDS footprint as round 5 (59.4 KB, 2 blocks/CU) but 4 waves/SIMD:
// ---- per-wave serial chain halves and TLP doubles -> latency hides.
__global__ __launch_bounds__(512, 4) void gram_kernel(
    const unsigned char* __restrict__ xb, const float* __restrict__ sq,
    const int* __restrict__ lab, double* __restrict__ cells) {
  __shared__ __align__(16) unsigned char sA[PANEL];
  __shared__ __align__(16) unsigned char sB[PANEL];

  const int t = threadIdx.x;
  const int b = (blockIdx.x & 7) * (NBLK / 8) + (blockIdx.x >> 3);  // XCD swizzle (2080%8==0)
  const int q = b / TPP, idx = b - q * TPP;        // row-pair decode
  const int n1 = NT - q;
  const int I = (idx < n1) ? q : NT - 1 - q;
  const int J = (idx < n1) ? q + idx : (NT - 1 - q) + (idx - n1);

  auto stage = [&](const unsigned char* g, unsigned char* sh) {
#pragma unroll
    for (int c = 0; c < 3; ++c) {
      int off = c * 8192 + t * 16;
      __builtin_amdgcn_global_load_lds((const AS1 void*)(g + off),
                                       (AS3 void*)(sh + off), 16, 0, 0);
    }
    if (t < 320) {                                 // 29696 - 24576 = 320*16
      int off = 24576 + t * 16;
      __builtin_amdgcn_global_load_lds((const AS1 void*)(g + off),
                                       (AS3 void*)(sh + off), 16, 0, 0);
    }
  };
  stage(xb + (size_t)I * PANEL, sA);
  stage(xb + (size_t)J * PANEL, sB);

  // ---- hoisted epilogue operands (ride the same vmcnt drain as staging) ----
  const int wid = t >> 6, lane = t & 63;
  const int col = lane & 15, quad = lane >> 4;
  const int waveM = (wid & 1) * 64, waveN = (wid >> 1) * 32;
  const int i0 = I * TB + waveM, j0 = J * TB + waveN;
  int labj[2];
  float sqj[2];
#pragma unroll
  for (int ni = 0; ni < 2; ++ni) {
    int j = j0 + ni * 16 + col;
    labj[ni] = lab[j];
    sqj[ni] = sq[j];
  }
  float4 sqi4[4];
  int4 li4[4];
#pragma unroll
  for (int mi = 0; mi < 4; ++mi) {
    sqi4[mi] = *(const float4*)(sq + i0 + mi * 16 + quad * 4);
    li4[mi] = *(const int4*)(lab + i0 + mi * 16 + quad * 4);
  }
  __syncthreads();                                 // drains staging vmcnt + barrier

  // ---- K-loop from LDS: 56 MFMA per wave ----
  f32x4 acc[4][2] = {};
  __builtin_amdgcn_s_setprio(1);
#pragma unroll
  for (int step = 0; step < NSTEP; ++step) {
    long a[4], bf[2];
#pragma unroll
    for (int mi = 0; mi < 4; ++mi)
      a[mi] = *(const long*)(sA + (waveM + mi * 16 + col) * KP + step * 32 + quad * 8);
#pragma unroll
    for (int ni = 0; ni < 2; ++ni)
      bf[ni] = *(const long*)(sB + (waveN + ni * 16 + col) * KP + step * 32 + quad * 8);
#pragma unroll
    for (int mi = 0; mi < 4; ++mi)
#pragma unroll
      for (int ni = 0; ni < 2; ++ni)
        acc[mi][ni] = __builtin_amdgcn_mfma_f32_16x16x32_fp8_fp8(
            a[mi], bf[ni], acc[mi][ni], 0, 0, 0);
  }
  __builtin_amdgcn_s_setprio(0);

  // ---- epilogue: D[m = quad*4 + r][n = col] (verified layout) ----
  float rs = 0.f, tot;
  if (I != J) {
#pragma unroll
    for (int mi = 0; mi < 4; ++mi) {
      float sqi[4] = {sqi4[mi].x, sqi4[mi].y, sqi4[mi].z, sqi4[mi].w};
      int li[4] = {li4[mi].x, li4[mi].y, li4[mi].z, li4[mi].w};
#pragma unroll
      for (int r = 0; r < 4; ++r)
#pragma unroll
        for (int ni = 0; ni < 2; ++ni) {
          float g = acc[mi][ni][r];
          float d2 = fmaxf(fmaf(-2.f, g, sqi[r] + sqj[ni]), 0.f);
          float dist = __builtin_amdgcn_sqrtf(d2);
          rs += (li[r] == labj[ni]) ? dist : -dist;
        }
    }
    tot = 2.f * rs;                                // mirror tile not launched
  } else {
#pragma unroll
    for (int mi = 0; mi < 4; ++mi) {
      float sqi[4] = {sqi4[mi].x, sqi4[mi].y, sqi4[mi].z, sqi4[mi].w};
      int li[4] = {li4[mi].x, li4[mi].y, li4[mi].z, li4[mi].w};
#pragma unroll
      for (int r = 0; r < 4; ++r) {
        int i = i0 + mi * 16 + quad * 4 + r;
#pragma unroll
        for (int ni = 0; ni < 2; ++ni) {
          int j = j0 + ni * 16 + col;
          float g = acc[mi][ni][r];
          float d2 = fmaxf(fmaf(-2.f, g, sqi[r] + sqj[ni]), 0.f);
          float dist = __builtin_amdgcn_sqrtf(d2);
          float c = (li[r] == labj[ni]) ? dist : -dist;
          rs += (i == j) ? 0.f : c;
        }
      }
    }
    tot = rs;
  }

  // ---- per-wave f64 scatter atomic (256 cells, spread in time: no contention) ----
#pragma unroll
  for (int m = 32; m; m >>= 1) tot += __shfl_xor(tot, m);
  if (lane == 0)
    atomicAdd(&cells[(b * 8 + wid) & (NCELL - 1)], (double)tot);
}

// ---------------- final mean (256 doubles only) ----------------
__global__ __launch_bounds__(256) void reduce_kernel(
    const double* __restrict__ cells, float* __restrict__ out) {
  __shared__ double wsum[4];
  double s = cells[threadIdx.x];
#pragma unroll
  for (int m = 32; m; m >>= 1) s += __shfl_xor(s, m);
  if ((threadIdx.x & 63) == 0) wsum[threadIdx.x >> 6] = s;
  __syncthreads();
  if (threadIdx.x == 0)
    out[0] = (float)((wsum[0] + wsum[1] + wsum[2] + wsum[3]) / (double)N);
}

extern "C" void kernel_launch(void* const* d_in, const int* in_sizes, int n_in,
                              void* d_out, int out_size, void* d_ws, size_t ws_size,
                              hipStream_t stream) {
  const float* x = (const float*)d_in[0];
  const int* labels = (const int*)d_in[1];
  char* ws = (char*)d_ws;
  unsigned char* xb = (unsigned char*)ws;                         // N*KP = 1.9 MB
  float* sq = (float*)(ws + (size_t)N * KP);                      // N*4
  int* lab = (int*)(ws + (size_t)N * KP + (size_t)N * 4);         // N*4
  double* cells = (double*)(ws + (size_t)N * KP + (size_t)N * 8); // 256*8
  float* out = (float*)d_out;

  prep_kernel<<<N / 4, 256, 0, stream>>>(x, labels, xb, sq, lab, cells);
  gram_kernel<<<NBLK, 512, 0, stream>>>(xb, sq, lab, cells);
  reduce_kernel<<<1, 256, 0, stream>>>(cells, out);
}

// Round 7
// 83.866 us; speedup vs baseline: 1.0136x; 1.0136x over previous
//
#include <hip/hip_runtime.h>
#include <hip/hip_fp8.h>

#define N 8192
#define D 200
#define KP 232             // fp8 row stride BYTES: 58 dwords -> optimal 4/bank ds_read_b64
#define NSTEP 7            // 7 * 32 = 224 K fed to MFMA (200 real + fp8-zero pad)
#define NBLK 4160          // sum_{q=0}^{63} (128-2q) 128x64 tiles; 4160 = 8*520
#define PANEL_A (128 * KP) // 29696 B
#define PANEL_B (64 * KP)  // 14848 B; LDS total 44544 B -> 3 blocks/CU
#define NCELL 256

typedef float f32x4 __attribute__((ext_vector_type(4)));
#define AS3 __attribute__((address_space(3)))
#define AS1 __attribute__((address_space(1)))

// ---- prep: cast to fp8 e4m3 (padded to KP), row norms from fp8-decoded ----
// Block 0 also zeroes the 256 reduction cells (workspace is poisoned each iter).
__global__ __launch_bounds__(256) void prep_kernel(
    const float* __restrict__ x, const int* __restrict__ labels,
    unsigned char* __restrict__ xb, float* __restrict__ sq,
    int* __restrict__ lab, double* __restrict__ cells) {
  if (blockIdx.x == 0) cells[threadIdx.x] = 0.0;   // NCELL == blockDim
  int row = blockIdx.x * 4 + (threadIdx.x >> 6);   // one wave per row
  int lane = threadIdx.x & 63;
  const float* xr = x + (size_t)row * D;
  unsigned char* xbr = xb + (size_t)row * KP;
  int k0 = lane * 4;
  float4 f = {0.f, 0.f, 0.f, 0.f};
  if (k0 < D) f = *(const float4*)(xr + k0);       // lane<50 fully in-bounds
  float s = 0.f;
  unsigned char q[4];
  float ff[4] = {f.x, f.y, f.z, f.w};
#pragma unroll
  for (int c = 0; c < 4; ++c) {
    float v = (k0 + c < D) ? ff[c] : 0.f;
    __hip_fp8_e4m3 h(v);                           // OCP e4m3 RNE
    q[c] = h.__x;
    float fb = (float)h;
    s += fb * fb;                                  // norm of the fp8-rounded row
  }
  if (k0 < KP) *(uchar4*)(xbr + k0) = *(uchar4*)q; // lanes 0..57 (56,57 write zeros)
#pragma unroll
  for (int m = 32; m; m >>= 1) s += __shfl_xor(s, m);
  if (lane == 0) {
    sq[row] = s;
    lab[row] = labels[row];
  }
}

// ---- gram: 128x64 tile per block, 44.5 KB LDS -> 3 blocks/CU so the
// ---- 3-phase chain {stage-wait, K-loop, epilogue} anti-phases across
// ---- blocks and the MFMA pipe stays fed. Uniform (gi<gj) predicate
// ---- handles diagonal-spanning strips; global x2.
__global__ __launch_bounds__(256, 3) void gram_kernel(
    const unsigned char* __restrict__ xb, const float* __restrict__ sq,
    const int* __restrict__ lab, double* __restrict__ cells) {
  __shared__ __align__(16) unsigned char sA[PANEL_A];
  __shared__ __align__(16) unsigned char sB[PANEL_B];

  const int t = threadIdx.x;
  const int b = (blockIdx.x & 7) * (NBLK / 8) + (blockIdx.x >> 3);  // XCD swizzle (4160%8==0)
  // pair decode: A-row pair pr handles q=pr (128-2pr strips) and q=63-pr (2pr+2)
  const int pr = b / 130, r = b - pr * 130;
  const int n1 = 128 - 2 * pr;
  const int q  = (r < n1) ? pr : 63 - pr;
  const int j2 = (r < n1) ? 2 * pr + r : 2 * (63 - pr) + (r - n1);

  auto stageA = [&](const unsigned char* g) {
#pragma unroll
    for (int c = 0; c < 7; ++c) {
      int off = c * 4096 + t * 16;
      __builtin_amdgcn_global_load_lds((const AS1 void*)(g + off),
                                       (AS3 void*)(sA + off), 16, 0, 0);
    }
    if (t < 64) {                                  // 29696 - 28672 = 64*16
      int off = 28672 + t * 16;
      __builtin_amdgcn_global_load_lds((const AS1 void*)(g + off),
                                       (AS3 void*)(sA + off), 16, 0, 0);
    }
  };
  auto stageB = [&](const unsigned char* g) {
#pragma unroll
    for (int c = 0; c < 3; ++c) {
      int off = c * 4096 + t * 16;
      __builtin_amdgcn_global_load_lds((const AS1 void*)(g + off),
                                       (AS3 void*)(sB + off), 16, 0, 0);
    }
    if (t < 160) {                                 // 14848 - 12288 = 160*16
      int off = 12288 + t * 16;
      __builtin_amdgcn_global_load_lds((const AS1 void*)(g + off),
                                       (AS3 void*)(sB + off), 16, 0, 0);
    }
  };
  stageA(xb + (size_t)q * PANEL_A);
  stageB(xb + (size_t)j2 * PANEL_B);

  // ---- hoisted epilogue operands (ride the same vmcnt drain as staging) ----
  const int wid = t >> 6, lane = t & 63;
  const int col = lane & 15, quad = lane >> 4;
  const int waveM = (wid & 1) * 64, waveN = (wid >> 1) * 32;
  const int i0 = q * 128 + waveM, j0 = j2 * 64 + waveN;
  int labj[2];
  float sqj[2];
#pragma unroll
  for (int ni = 0; ni < 2; ++ni) {
    int j = j0 + ni * 16 + col;
    labj[ni] = lab[j];
    sqj[ni] = sq[j];
  }
  float4 sqi4[4];
  int4 li4[4];
#pragma unroll
  for (int mi = 0; mi < 4; ++mi) {
    sqi4[mi] = *(const float4*)(sq + i0 + mi * 16 + quad * 4);
    li4[mi] = *(const int4*)(lab + i0 + mi * 16 + quad * 4);
  }
  __syncthreads();                                 // drains staging vmcnt + barrier

  // ---- K-loop from LDS: 56 MFMA per wave (64x32 quadrant, round-6 shape) ----
  f32x4 acc[4][2] = {};
  __builtin_amdgcn_s_setprio(1);
#pragma unroll
  for (int step = 0; step < NSTEP; ++step) {
    long a[4], bf[2];
#pragma unroll
    for (int mi = 0; mi < 4; ++mi)
      a[mi] = *(const long*)(sA + (waveM + mi * 16 + col) * KP + step * 32 + quad * 8);
#pragma unroll
    for (int ni = 0; ni < 2; ++ni)
      bf[ni] = *(const long*)(sB + (waveN + ni * 16 + col) * KP + step * 32 + quad * 8);
#pragma unroll
    for (int mi = 0; mi < 4; ++mi)
#pragma unroll
      for (int ni = 0; ni < 2; ++ni)
        acc[mi][ni] = __builtin_amdgcn_mfma_f32_16x16x32_fp8_fp8(
            a[mi], bf[ni], acc[mi][ni], 0, 0, 0);
  }
  __builtin_amdgcn_s_setprio(0);

  // ---- epilogue: D[m = quad*4 + r][n = col]; count only gi<gj, x2 global ----
  float rs = 0.f;
#pragma unroll
  for (int mi = 0; mi < 4; ++mi) {
    float sqi[4] = {sqi4[mi].x, sqi4[mi].y, sqi4[mi].z, sqi4[mi].w};
    int li[4] = {li4[mi].x, li4[mi].y, li4[mi].z, li4[mi].w};
#pragma unroll
    for (int r4 = 0; r4 < 4; ++r4) {
      int gi = i0 + mi * 16 + quad * 4 + r4;
#pragma unroll
      for (int ni = 0; ni < 2; ++ni) {
        int gj = j0 + ni * 16 + col;
        float g = acc[mi][ni][r4];
        float d2 = fmaxf(fmaf(-2.f, g, sqi[r4] + sqj[ni]), 0.f);
        float dist = __builtin_amdgcn_sqrtf(d2);
        float c = (li[r4] == labj[ni]) ? dist : -dist;
        rs += (gi < gj) ? c : 0.f;
      }
    }
  }
  float tot = 2.f * rs;                            // every unordered pair counted once

  // ---- per-wave f64 scatter atomic (256 cells: no contention) ----
#pragma unroll
  for (int m = 32; m; m >>= 1) tot += __shfl_xor(tot, m);
  if (lane == 0)
    atomicAdd(&cells[(b * 4 + wid) & (NCELL - 1)], (double)tot);
}

// ---------------- final mean (256 doubles only) ----------------
__global__ __launch_bounds__(256) void reduce_kernel(
    const double* __restrict__ cells, float* __restrict__ out) {
  __shared__ double wsum[4];
  double s = cells[threadIdx.x];
#pragma unroll
  for (int m = 32; m; m >>= 1) s += __shfl_xor(s, m);
  if ((threadIdx.x & 63) == 0) wsum[threadIdx.x >> 6] = s;
  __syncthreads();
  if (threadIdx.x == 0)
    out[0] = (float)((wsum[0] + wsum[1] + wsum[2] + wsum[3]) / (double)N);
}

extern "C" void kernel_launch(void* const* d_in, const int* in_sizes, int n_in,
                              void* d_out, int out_size, void* d_ws, size_t ws_size,
                              hipStream_t stream) {
  const float* x = (const float*)d_in[0];
  const int* labels = (const int*)d_in[1];
  char* ws = (char*)d_ws;
  unsigned char* xb = (unsigned char*)ws;                         // N*KP = 1.9 MB
  float* sq = (float*)(ws + (size_t)N * KP);                      // N*4
  int* lab = (int*)(ws + (size_t)N * KP + (size_t)N * 4);         // N*4
  double* cells = (double*)(ws + (size_t)N * KP + (size_t)N * 8); // 256*8
  float* out = (float*)d_out;

  prep_kernel<<<N / 4, 256, 0, stream>>>(x, labels, xb, sq, lab, cells);
  gram_kernel<<<NBLK, 256, 0, stream>>>(xb, sq, lab, cells);
  reduce_kernel<<<1, 256, 0, stream>>>(cells, out);
}